// Round 4
// baseline (457.580 us; speedup 1.0000x reference)
//
#include <hip/hip_runtime.h>

#define NC   16      // channels
#define NP   48      // perception channels = 3*NC
#define NH   128     // hidden
#define HDIM 256
#define WDIM 256
#define HW   (HDIM*WDIM)

#define PSTR 48      // sP row stride (bf16): exactly NP
#define HSTR 136     // H row stride (bf16)

typedef __attribute__((ext_vector_type(8))) short short8;  // 8 bf16 = 1 MFMA operand
typedef __attribute__((ext_vector_type(4))) float f32x4;   // MFMA accumulator / 16B store
typedef __attribute__((ext_vector_type(4))) int   int4v;   // 16B LDS store
typedef __attribute__((ext_vector_type(2))) int   int2v;   // 8B LDS store

__device__ __forceinline__ unsigned cvt_pk(float lo, float hi) {
    unsigned r;
    asm("v_cvt_pk_bf16_f32 %0, %1, %2" : "=v"(r) : "v"(lo), "v"(hi));
    return r;
}
__device__ __forceinline__ short f2bf(float f) {
    unsigned u = __float_as_uint(f);
    u += 0x7FFFu + ((u >> 16) & 1u);   // RNE
    return (short)(u >> 16);
}
__device__ __forceinline__ float b2f(short s) {
    return __uint_as_float((unsigned)(unsigned short)s << 16);
}

__global__ __launch_bounds__(256, 4) void nca_mfma_kernel(
    const float* __restrict__ grid,
    const float* __restrict__ noise,
    const float* __restrict__ w1,
    const float* __restrict__ b1,
    const float* __restrict__ w2,
    const float* __restrict__ b2,
    float* __restrict__ out)
{
    // w1 in MFMA-B-fragment layout, LIVE through phase 4:
    // [n][ t=0: 512 shorts (64 lanes x 8) | t=1: 256 shorts (lanes 0..31 x 8) ]
    __shared__ short sW1F[8 * 768];          // 12288 B
    // sP [256 px][48]: perception matrix for phase 4. The SAME 24576 B first
    // serve as the raw-row staging buffer [3 rows][16 ch][256 px] bf16
    // (row-block layout: entry (row,ch,px) at (row*16+ch)*256 + px), then as
    // per-wave H overlay in phase 4. Total LDS 36864 B -> 4 blocks/CU.
    __shared__ short sP[HDIM * PSTR];        // 24576 B

    const int tid  = threadIdx.x;
    // XCD band swizzle: round-robin dispatch puts id%8 on XCD id%8; give each
    // XCD one contiguous 32-row band per batch so halo rows are L2-shared.
    const int id   = blockIdx.x;
    const int k    = id >> 3;
    const int b    = k >> 5;                  // 32 batches
    const int y    = (id & 7) * 32 + (k & 31);

    const int wv   = tid >> 6;
    const int lane = tid & 63;
    const int q    = lane >> 4;
    const int l15  = lane & 15;

    // ---------- Phase 0: stage w1 to LDS in fragment layout ----------
    {
        const int o = tid >> 1, half = tid & 1;   // 2 threads per w1 row
        const float* src = w1 + o * NP + 24 * half;
        const int n = o >> 4, r15 = o & 15;
        #pragma unroll
        for (int g = 0; g < 3; ++g) {
            const int k0 = 24 * half + 8 * g;
            const int tt = k0 >> 5, qq = (k0 & 31) >> 3;
            unsigned u0 = cvt_pk(src[8*g+0], src[8*g+1]);
            unsigned u1 = cvt_pk(src[8*g+2], src[8*g+3]);
            unsigned u2 = cvt_pk(src[8*g+4], src[8*g+5]);
            unsigned u3 = cvt_pk(src[8*g+6], src[8*g+7]);
            int4v v = {(int)u0, (int)u1, (int)u2, (int)u3};
            *(int4v*)&sW1F[n*768 + (tt ? 512 : 0) + (qq*16 + r15)*8] = v;
        }
    }

    // ---------- Phase 1a: issue ALL stencil loads (coalesced, 12/thread) ----------
    // chunk rc = wv + 4j (wave-uniform): row = rc>>4 (0..2), ch = rc&15
    float4 vbuf[12];
    {
        const int seg = tid & 63;
        const size_t gbase = (size_t)b * NC * HW + 4 * seg;
        #pragma unroll
        for (int j = 0; j < 12; ++j) {
            const int rc = wv + 4*j;
            const int row = rc >> 4, ch = rc & 15;
            int ry = y - 1 + row; ry = ry < 0 ? 0 : (ry > 255 ? 255 : ry);
            vbuf[j] = *(const float4*)(grid + gbase + (size_t)ch * HW + (size_t)ry * WDIM);
        }
    }

    // w2 B-frags straight from global (permuted o-space: o' = a*8+j' <-> o = j'*16+a,
    // a = 4t+q; H is written with the same permutation so the contraction matches).
    short8 w2f[4];
    #pragma unroll
    for (int t = 0; t < 4; ++t) {
        short8 v;
        #pragma unroll
        for (int jj = 0; jj < 8; ++jj) v[jj] = f2bf(w2[l15 * NH + jj*16 + 4*t + q]);
        w2f[t] = v;
    }
    float b1v[8];
    #pragma unroll
    for (int n = 0; n < 8; ++n) b1v[n] = b1[16*n + l15];
    const float b2v = b2[l15];

    // ---------- Phase 1b: store raw rows (bf16) into staging ----------
    {
        const int seg = tid & 63;
        #pragma unroll
        for (int j = 0; j < 12; ++j) {
            const int rc = wv + 4*j, row = rc >> 4;
            float4 v = vbuf[j];
            const bool zr = (row == 0 && y == 0) || (row == 2 && y == 255); // SAME pad
            if (zr) { float4 z = {0,0,0,0}; v = z; }
            int2v pv = {(int)cvt_pk(v.x, v.y), (int)cvt_pk(v.z, v.w)};
            *(int2v*)&sP[rc * 256 + seg * 4] = pv;
        }
    }
    __syncthreads();   // staging complete (and sW1F, for later)

    // ---------- Phase 1c: stencil from LDS (thread = pixel x) ----------
    unsigned pk[24];
    {
        const int x = tid;
        const bool xm = (x > 0), xp = (x < 255);
        const int xl = xm ? x - 1 : 0;
        const int xr = xp ? x + 1 : 255;
        float carry = 0.f;
        #pragma unroll
        for (int c = 0; c < 16; ++c) {
            const short* bT = &sP[c * 256];           // row T; M at +4096, B at +8192
            const float tl0 = b2f(bT[xl]),        tm = b2f(bT[x]),        tr0 = b2f(bT[xr]);
            const float ml0 = b2f(bT[4096 + xl]), mm = b2f(bT[4096 + x]), mr0 = b2f(bT[4096 + xr]);
            const float bl0 = b2f(bT[8192 + xl]), bm = b2f(bT[8192 + x]), br0 = b2f(bT[8192 + xr]);
            const float tl = xm ? tl0 : 0.f, tr = xp ? tr0 : 0.f;
            const float ml = xm ? ml0 : 0.f, mr = xp ? mr0 : 0.f;
            const float bl = xm ? bl0 : 0.f, br = xp ? br0 : 0.f;
            const float p1 = (tl + tr + 2.f*ml - 2.f*mr + bl - br) * 0.125f;
            const float p2 = (tl + 2.f*tm + tr - bl - 2.f*bm - br) * 0.125f;
            if (c & 1) { pk[(3*c - 1) / 2] = cvt_pk(carry, mm); pk[(3*c + 1) / 2] = cvt_pk(p1, p2); }
            else       { pk[3*c / 2]       = cvt_pk(mm, p1);    carry = p2; }
        }
    }
    __syncthreads();   // all staging reads done; safe to overwrite with sP rows

    {
        short* rowp = &sP[tid * PSTR];
        #pragma unroll
        for (int i = 0; i < 6; ++i) {
            int4v v = {(int)pk[4*i], (int)pk[4*i+1], (int)pk[4*i+2], (int)pk[4*i+3]};
            *(int4v*)&rowp[8*i] = v;
        }
    }
    __syncthreads();   // sP fully built

    // ---------- Phase 4: MFMA MLP over this wave's 4 pixel-tiles ----------
    // prefetch A-frags for mt=1..3 (their sP rows get overlaid by H below)
    short8 aF0[3], aF1[3];
    #pragma unroll
    for (int m = 1; m < 4; ++m) {
        const short* pr = &sP[((wv*4 + m)*16 + l15) * PSTR];
        aF0[m-1] = *(const short8*)&pr[8*q];
        short8 a1 = {};
        if (q < 2) a1 = *(const short8*)&pr[32 + 8*q];   // k=32..47 real; q>=2 -> zero
        aF1[m-1] = a1;
    }
    // H overlays own-wave sP rows 16.. (4352 B needed, 4608 B available; 16B-aligned)
    short* Hb = &sP[(wv*64 + 16) * PSTR];

    #pragma unroll
    for (int mt = 0; mt < 4; ++mt) {
        short8 a0, a1;
        if (mt == 0) {       // rows 0..15 of own span are never overlaid: read JIT
            const short* pr = &sP[(wv*64 + l15) * PSTR];
            a0 = *(const short8*)&pr[8*q];
            short8 z = {}; a1 = z;
            if (q < 2) a1 = *(const short8*)&pr[32 + 8*q];
        } else { a0 = aF0[mt-1]; a1 = aF1[mt-1]; }

        f32x4 acc[8];
        #pragma unroll
        for (int n = 0; n < 8; ++n) { f32x4 t4 = {b1v[n], b1v[n], b1v[n], b1v[n]}; acc[n] = t4; }
        #pragma unroll
        for (int n = 0; n < 8; ++n) {      // k = 0..31
            const short8 bf0 = *(const short8*)&sW1F[n*768 + lane*8];
            acc[n] = __builtin_amdgcn_mfma_f32_16x16x32_bf16(a0, bf0, acc[n], 0, 0, 0);
        }
        #pragma unroll
        for (int n = 0; n < 8; ++n) {      // k = 32..63 (real data only in lanes 0..31)
            short8 bf1 = {};
            if (lane < 32) bf1 = *(const short8*)&sW1F[n*768 + 512 + lane*8];
            acc[n] = __builtin_amdgcn_mfma_f32_16x16x32_bf16(a1, bf1, acc[n], 0, 0, 0);
        }

        // relu -> bf16 -> H' [m=q*4+r][o'=l15*8+n] (one b128 per r)
        #pragma unroll
        for (int rr = 0; rr < 4; ++rr) {
            unsigned h0 = cvt_pk(fmaxf(acc[0][rr], 0.f), fmaxf(acc[1][rr], 0.f));
            unsigned h1 = cvt_pk(fmaxf(acc[2][rr], 0.f), fmaxf(acc[3][rr], 0.f));
            unsigned h2 = cvt_pk(fmaxf(acc[4][rr], 0.f), fmaxf(acc[5][rr], 0.f));
            unsigned h3 = cvt_pk(fmaxf(acc[6][rr], 0.f), fmaxf(acc[7][rr], 0.f));
            int4v v = {(int)h0, (int)h1, (int)h2, (int)h3};
            *(int4v*)&Hb[(q*4 + rr) * HSTR + l15 * 8] = v;
        }
        // GEMM2: A[m=l15][k=o'=32t+8q+j] from H', B = w2f (same permutation)
        f32x4 acc2 = {b2v, b2v, b2v, b2v};
        #pragma unroll
        for (int t = 0; t < 4; ++t) {
            const short8 af = *(const short8*)&Hb[l15 * HSTR + 32*t + 8*q];
            acc2 = __builtin_amdgcn_mfma_f32_16x16x32_bf16(af, w2f[t], acc2, 0, 0, 0);
        }
        // Epilogue straight from C-layout: lane = (channel j=l15, pixels px0+4q..+3)
        const int px0 = (wv*4 + mt) * 16;
        const int px  = px0 + 4*q;
        const size_t gi = (size_t)b * NC * HW + (size_t)l15 * HW + (size_t)y * WDIM + px;
        const float4 g  = *(const float4*)&grid[gi];   // L2-hot from phase 1 (same XCD)
        const float4 nz = *(const float4*)&noise[(size_t)b * HW + (size_t)y * WDIM + px];
        f32x4 o;
        o[0] = fminf(fmaxf(g.x + acc2[0] * (nz.x < 0.5f ? 1.f : 0.f), -2.f), 2.f);
        o[1] = fminf(fmaxf(g.y + acc2[1] * (nz.y < 0.5f ? 1.f : 0.f), -2.f), 2.f);
        o[2] = fminf(fmaxf(g.z + acc2[2] * (nz.z < 0.5f ? 1.f : 0.f), -2.f), 2.f);
        o[3] = fminf(fmaxf(g.w + acc2[3] * (nz.w < 0.5f ? 1.f : 0.f), -2.f), 2.f);
        // write-once data: nt store bypasses L2 (tests the RFO/write-amp theory);
        // ext_vector type (f32x4), since the builtin rejects HIP_vector_type
        __builtin_nontemporal_store(o, (f32x4*)&out[gi]);
    }
}

extern "C" void kernel_launch(void* const* d_in, const int* in_sizes, int n_in,
                              void* d_out, int out_size, void* d_ws, size_t ws_size,
                              hipStream_t stream) {
    const float* grid  = (const float*)d_in[0];
    const float* noise = (const float*)d_in[1];
    const float* w1    = (const float*)d_in[2];
    const float* b1    = (const float*)d_in[3];
    const float* w2    = (const float*)d_in[4];
    const float* b2    = (const float*)d_in[5];
    float* out = (float*)d_out;

    dim3 g(32 * 256);   // one block per (batch, row), XCD-banded inside the kernel
    nca_mfma_kernel<<<g, 256, 0, stream>>>(grid, noise, w1, b1, w2, b2, out);
}